// Round 1
// baseline (69.796 us; speedup 1.0000x reference)
//
#include <hip/hip_runtime.h>

#define OUT_H 64
#define OUT_W 64
#define DEPTH 65
#define IMG_H 128
#define IMG_W 128
#define NC    32

__device__ __forceinline__ int clampi(int v, int lo, int hi) {
    return v < lo ? lo : (v > hi ? hi : v);
}

// One thread per (output pixel, channel). 65-deep k loop; gathers only when
// the depth weight zw != 0 (exact skip: padded volume is zero except z==32).
__global__ __launch_bounds__(256) void BilinearInterpolation_60670708023631_kernel(
    const float* __restrict__ img,   // (128,128,32)
    const float* __restrict__ T,     // (12) = 3x4 affine
    float* __restrict__ out)         // (64,64,32)
{
    const int tid = blockIdx.x * blockDim.x + threadIdx.x;
    const int c   = tid & (NC - 1);
    const int p   = tid >> 5;           // pixel id 0..4095
    const int oj  = p & (OUT_W - 1);    // x index (fast dim of meshgrid 'xy')
    const int oi  = p >> 6;             // y index

    // transform is 12 floats; every lane reads it (L1/L2 broadcast)
    const float t00 = T[0], t01 = T[1], t02 = T[2],  t03 = T[3];
    const float t10 = T[4], t11 = T[5], t12 = T[6],  t13 = T[7];
    const float t20 = T[8], t21 = T[9], t22 = T[10], t23 = T[11];

    // jnp.linspace(-1,1,64): delta = 2/63 (rounded), out = i*delta + (-1)
    const float dxy = __fdiv_rn(2.0f, 63.0f);
    const float gx  = __fadd_rn(__fmul_rn((float)oj, dxy), -1.0f);
    const float gy  = __fadd_rn(__fmul_rn((float)oi, dxy), -1.0f);

    float acc = 0.0f;

    for (int k = 0; k < DEPTH; ++k) {
        // z linspace delta = 2/64 = 0.03125: exact in f32 for all k
        const float gz = __fadd_rn(__fmul_rn((float)k, 0.03125f), -1.0f);

        // einsum row: fma-sequential like a GEMM K-loop (K=4, last col is ones)
        float sx = __fmul_rn(t00, gx); sx = fmaf(t01, gy, sx); sx = fmaf(t02, gz, sx); sx = __fadd_rn(sx, t03);
        float sy = __fmul_rn(t10, gx); sy = fmaf(t11, gy, sy); sy = fmaf(t12, gz, sy); sy = __fadd_rn(sy, t13);
        float sz = __fmul_rn(t20, gx); sz = fmaf(t21, gy, sz); sz = fmaf(t22, gz, sz); sz = __fadd_rn(sz, t23);

        // 0.5*(s+1)*W — multiplications by powers of two are exact; *65 rounds once
        const float x = __fmul_rn(__fmul_rn(__fadd_rn(sx, 1.0f), 0.5f), 128.0f);
        const float y = __fmul_rn(__fmul_rn(__fadd_rn(sy, 1.0f), 0.5f), 128.0f);
        const float z = __fmul_rn(__fmul_rn(__fadd_rn(sz, 1.0f), 0.5f), 65.0f);

        // astype(int32) truncates toward zero, then clip
        const int izt = (int)z;
        const int z0  = clampi(izt,     0, DEPTH - 1);
        const int z1  = clampi(izt + 1, 0, DEPTH - 1);

        float zw = 0.0f;
        if (z0 == 32) zw = __fadd_rn(zw, __fsub_rn((float)z1, z));
        if (z1 == 32) zw = __fadd_rn(zw, __fsub_rn(z, (float)z0));

        if (zw != 0.0f) {
            const int ixt = (int)x;
            const int x0  = clampi(ixt,     0, IMG_W - 1);
            const int x1  = clampi(ixt + 1, 0, IMG_W - 1);
            const int iyt = (int)y;
            const int y0  = clampi(iyt,     0, IMG_H - 1);
            const int y1  = clampi(iyt + 1, 0, IMG_H - 1);

            const float fx0 = __fsub_rn((float)x1, x);   // pairs with y0 row
            const float fx1 = __fsub_rn(x, (float)x0);   // pairs with y1 row
            const float fy0 = __fsub_rn((float)y1, y);   // pairs with x0 col
            const float fy1 = __fsub_rn(y, (float)y0);   // pairs with x1 col

            const float v00 = img[((y0 * IMG_W) + x0) * NC + c];
            const float v01 = img[((y0 * IMG_W) + x1) * NC + c];
            const float v10 = img[((y1 * IMG_W) + x0) * NC + c];
            const float v11 = img[((y1 * IMG_W) + x1) * NC + c];

            // faithful swapped pairing: term(i,j) = fx_i * fy_j * V[y_i, x_j]
            const float bil = fx0 * (fy0 * v00 + fy1 * v01)
                            + fx1 * (fy0 * v10 + fy1 * v11);
            acc = fmaf(zw, bil, acc);
        }
    }

    out[tid] = acc;   // (64,64,32) contiguous, coalesced
}

extern "C" void kernel_launch(void* const* d_in, const int* in_sizes, int n_in,
                              void* d_out, int out_size, void* d_ws, size_t ws_size,
                              hipStream_t stream) {
    const float* img = (const float*)d_in[0];   // (1,128,128,32) f32
    const float* T   = (const float*)d_in[1];   // (1,12) f32
    float* out       = (float*)d_out;           // (1,64,64,32) f32

    const int total  = OUT_H * OUT_W * NC;      // 131072 threads
    dim3 grid(total / 256), block(256);
    hipLaunchKernelGGL(BilinearInterpolation_60670708023631_kernel,
                       grid, block, 0, stream, img, T, out);
}

// Round 7
// 66.205 us; speedup vs baseline: 1.0542x; 1.0542x over previous
//
#include <hip/hip_runtime.h>

#define OUT_H 64
#define OUT_W 64
#define DEPTH 65
#define IMG_H 128
#define IMG_W 128
#define NC    32

__device__ __forceinline__ int clampi(int v, int lo, int hi) {
    return v < lo ? lo : (v > hi ? hi : v);
}

// One thread per (output pixel, channel). z(k) is affine in k, and the depth
// weight zw is nonzero only for trunc(z) in {31,32}  (z in [31,33)) -- solve
// that k-window analytically and run the exact same inner body on it only.
// Skipped iterations contributed exactly 0.0, so output is bit-identical to
// the full 65-iteration loop.
__global__ __launch_bounds__(256) void BilinearInterpolation_60670708023631_kernel(
    const float* __restrict__ img,   // (128,128,32)
    const float* __restrict__ T,     // (12) = 3x4 affine
    float* __restrict__ out)         // (64,64,32)
{
    const int tid = blockIdx.x * blockDim.x + threadIdx.x;
    const int c   = tid & (NC - 1);
    const int p   = tid >> 5;           // pixel id 0..4095
    const int oj  = p & (OUT_W - 1);    // x index (fast dim of meshgrid 'xy')
    const int oi  = p >> 6;             // y index

    const float t00 = T[0], t01 = T[1], t02 = T[2],  t03 = T[3];
    const float t10 = T[4], t11 = T[5], t12 = T[6],  t13 = T[7];
    const float t20 = T[8], t21 = T[9], t22 = T[10], t23 = T[11];

    // jnp.linspace(-1,1,64): delta = 2/63 (rounded), out = i*delta + (-1)
    const float dxy = __fdiv_rn(2.0f, 63.0f);
    const float gx  = __fadd_rn(__fmul_rn((float)oj, dxy), -1.0f);
    const float gy  = __fadd_rn(__fmul_rn((float)oi, dxy), -1.0f);

    // ---- analytic k-window: z(k) ~= A + B*k, contributing iff z in [31,33) ----
    // A = z at k=0 (gz=-1), computed with the same op sequence as the loop body
    float sz0 = __fmul_rn(t20, gx); sz0 = fmaf(t21, gy, sz0); sz0 = fmaf(t22, -1.0f, sz0); sz0 = __fadd_rn(sz0, t23);
    const float A = __fmul_rn(__fmul_rn(__fadd_rn(sz0, 1.0f), 0.5f), 65.0f);
    const float B = t22 * 1.015625f;   // 65*0.5*0.03125 * t22

    int klo = 0, khi = DEPTH - 1;
    if (fabsf(B) >= 0.01f) {
        const float ka = (31.0f - A) / B;
        const float kb = (33.0f - A) / B;
        const float kmin = fminf(ka, kb), kmax = fmaxf(ka, kb);
        klo = clampi((int)floorf(kmin) - 1, 0, DEPTH - 1);
        khi = clampi((int)ceilf(kmax) + 1, 0, DEPTH - 1);
    }

    float acc = 0.0f;

    for (int k = klo; k <= khi; ++k) {
        // z linspace delta = 2/64 = 0.03125: exact in f32 for all k
        const float gz = __fadd_rn(__fmul_rn((float)k, 0.03125f), -1.0f);

        float sz = __fmul_rn(t20, gx); sz = fmaf(t21, gy, sz); sz = fmaf(t22, gz, sz); sz = __fadd_rn(sz, t23);
        const float z = __fmul_rn(__fmul_rn(__fadd_rn(sz, 1.0f), 0.5f), 65.0f);

        const int izt = (int)z;        // trunc toward zero, then clip
        const int z0  = clampi(izt,     0, DEPTH - 1);
        const int z1  = clampi(izt + 1, 0, DEPTH - 1);

        float zw = 0.0f;
        if (z0 == 32) zw = __fadd_rn(zw, __fsub_rn((float)z1, z));
        if (z1 == 32) zw = __fadd_rn(zw, __fsub_rn(z, (float)z0));

        if (zw != 0.0f) {
            float sx = __fmul_rn(t00, gx); sx = fmaf(t01, gy, sx); sx = fmaf(t02, gz, sx); sx = __fadd_rn(sx, t03);
            float sy = __fmul_rn(t10, gx); sy = fmaf(t11, gy, sy); sy = fmaf(t12, gz, sy); sy = __fadd_rn(sy, t13);
            const float x = __fmul_rn(__fmul_rn(__fadd_rn(sx, 1.0f), 0.5f), 128.0f);
            const float y = __fmul_rn(__fmul_rn(__fadd_rn(sy, 1.0f), 0.5f), 128.0f);

            const int ixt = (int)x;
            const int x0  = clampi(ixt,     0, IMG_W - 1);
            const int x1  = clampi(ixt + 1, 0, IMG_W - 1);
            const int iyt = (int)y;
            const int y0  = clampi(iyt,     0, IMG_H - 1);
            const int y1  = clampi(iyt + 1, 0, IMG_H - 1);

            const float fx0 = __fsub_rn((float)x1, x);   // pairs with y0 row
            const float fx1 = __fsub_rn(x, (float)x0);   // pairs with y1 row
            const float fy0 = __fsub_rn((float)y1, y);   // pairs with x0 col
            const float fy1 = __fsub_rn(y, (float)y0);   // pairs with x1 col

            const float v00 = img[((y0 * IMG_W) + x0) * NC + c];
            const float v01 = img[((y0 * IMG_W) + x1) * NC + c];
            const float v10 = img[((y1 * IMG_W) + x0) * NC + c];
            const float v11 = img[((y1 * IMG_W) + x1) * NC + c];

            // faithful swapped pairing: term(i,j) = fx_i * fy_j * V[y_i, x_j]
            const float bil = fx0 * (fy0 * v00 + fy1 * v01)
                            + fx1 * (fy0 * v10 + fy1 * v11);
            acc = fmaf(zw, bil, acc);
        }
    }

    out[tid] = acc;   // (64,64,32) contiguous, coalesced
}

extern "C" void kernel_launch(void* const* d_in, const int* in_sizes, int n_in,
                              void* d_out, int out_size, void* d_ws, size_t ws_size,
                              hipStream_t stream) {
    const float* img = (const float*)d_in[0];   // (1,128,128,32) f32
    const float* T   = (const float*)d_in[1];   // (1,12) f32
    float* out       = (float*)d_out;           // (1,64,64,32) f32

    const int total  = OUT_H * OUT_W * NC;      // 131072 threads
    dim3 grid(total / 256), block(256);
    hipLaunchKernelGGL(BilinearInterpolation_60670708023631_kernel,
                       grid, block, 0, stream, img, T, out);
}